// Round 5
// baseline (376.339 us; speedup 1.0000x reference)
//
#include <hip/hip_runtime.h>

typedef float  f32x4 __attribute__((ext_vector_type(4)));
typedef short  s16x8 __attribute__((ext_vector_type(8)));

#define PK 256   // panel K-span (floats); LDS row = 1KB, 64 x 16B chunks

typedef const __attribute__((address_space(1))) float* gas1f;
typedef __attribute__((address_space(3))) float*       las3f;

__device__ __forceinline__ short f2bf(float f) {
  unsigned u = __builtin_bit_cast(unsigned, f);
  u += 0x7FFFu + ((u >> 16) & 1u);   // round-to-nearest-even
  return (short)(u >> 16);
}

// ---------------------------------------------------------------------------
// Kernel 1: Y^T build.  Yt[c][k] = bf16( sum_d x[k][d] * W[d][c] )
// Kpad multiple of 256, zero-filled.  Offsets (elements):
//  v2v 0 (Kpad 6144) | v2e 196608 | e2e 393216 (Kpad 12032) | e2f 778240
//  f2f 1163264 (Kpad 8192); total 1425408 elems = 2.85 MB.
// ---------------------------------------------------------------------------
__global__ __launch_bounds__(256) void build_yt(
    const float* __restrict__ xv, const float* __restrict__ xe,
    const float* __restrict__ xf,
    const float* __restrict__ Wv2v, const float* __restrict__ Wv2e,
    const float* __restrict__ We2e, const float* __restrict__ We2f,
    const float* __restrict__ Wf2f, short* __restrict__ Yt)
{
  int bid = blockIdx.x;
  const float* x; const float* W; int K, Kpad; size_t yoff;
  if (bid < 24)       { x=xv; W=Wv2v; K=6000;  Kpad=6144;  yoff=0;       }
  else if (bid < 48)  { x=xv; W=Wv2e; K=6000;  Kpad=6144;  yoff=196608;  bid-=24; }
  else if (bid < 95)  { x=xe; W=We2e; K=12000; Kpad=12032; yoff=393216;  bid-=48; }
  else if (bid < 142) { x=xe; W=We2f; K=12000; Kpad=12032; yoff=778240;  bid-=95; }
  else                { x=xf; W=Wf2f; K=8000;  Kpad=8192;  yoff=1163264; bid-=142; }

  __shared__ float Wl[32][32];
  int tid = threadIdx.x;
  #pragma unroll
  for (int i = 0; i < 4; ++i) {
    int e = tid + i * 256;
    Wl[e >> 5][e & 31] = W[e];
  }
  __syncthreads();

  int row = bid * 256 + tid;
  if (row >= Kpad) return;

  float acc[32];
  #pragma unroll
  for (int c = 0; c < 32; ++c) acc[c] = 0.f;

  if (row < K) {
    const float* xp = x + (size_t)row * 32;
    float xr[32];
    #pragma unroll
    for (int i = 0; i < 8; ++i) {
      f32x4 v = *(const f32x4*)(xp + i * 4);
      xr[i*4+0] = v.x; xr[i*4+1] = v.y; xr[i*4+2] = v.z; xr[i*4+3] = v.w;
    }
    #pragma unroll
    for (int d = 0; d < 32; ++d) {
      float xd = xr[d];
      #pragma unroll
      for (int c = 0; c < 32; ++c) acc[c] += xd * Wl[d][c];
    }
  }
  #pragma unroll
  for (int c = 0; c < 32; ++c)
    Yt[yoff + (size_t)c * Kpad + row] = f2bf(acc[c]);
}

// ---------------------------------------------------------------------------
// Kernel 2: skinny GEMM.
//  - A staged in LDS panels [16][256]f (32KB dbuf), 1KB-per-row DMA bursts
//  - 16B-chunk XOR swizzle (slot c holds global chunk c^(r&7)): pre-swizzled
//    DMA source + swizzled ds_read -> conflict-free at PSTR=256
//  - counted-vmcnt pipeline; B prefetched to REGS at top of iter (FIFO:
//    stage(p) < B(p) < stage(p+1)) so compute touches no VMEM
//  - segments merged into one panel walk (no mid-block drain)
// ---------------------------------------------------------------------------
struct SegD { const float* G; const short* Y; int K, Kp, np; };

__device__ __forceinline__ void resolve(const SegD& s0, const SegD& s1, int idx,
                                        const SegD*& s, int& pn) {
  if (idx < s0.np) { s = &s0; pn = idx; }
  else             { s = &s1; pn = idx - s0.np; }
}

__device__ __forceinline__ int dma4(const SegD& s0, const SegD& s1, int idx, int npT) {
  if (idx >= npT) return 0;
  const SegD* s; int pn; resolve(s0, s1, idx, s, pn);
  return ((pn + 1) * PK <= s->K) ? 4 : 0;
}

__device__ __forceinline__ void stage_idx(
    const SegD& s0, const SegD& s1, int idx, int npT, int row0, int lane, int w,
    float (*panel)[16][PK])
{
  if (idx >= npT) return;
  const SegD* s; int pn; resolve(s0, s1, idx, s, pn);
  int bb = idx & 1;
  if ((pn + 1) * PK <= s->K) {         // full panel: 1KB DMA burst per row
    #pragma unroll
    for (int j = 0; j < 4; ++j) {
      int rr = 4 * w + j;
      const float* src = s->G + (size_t)(row0 + rr) * s->K + pn * PK
                       + ((lane ^ (rr & 7)) << 2);      // pre-swizzled source
      __builtin_amdgcn_global_load_lds((gas1f)src,
                                       (las3f)&panel[bb][rr][0], 16, 0, 2 /*nt*/);
    }
  } else {                             // tail: reg-staged, masked, zero-filled
    #pragma unroll
    for (int j = 0; j < 4; ++j) {
      int rr = 4 * w + j;
      int k = pn * PK + ((lane ^ (rr & 7)) << 2);
      f32x4 v = {0.f, 0.f, 0.f, 0.f};
      if (k < s->K) v = *(const f32x4*)(s->G + (size_t)(row0 + rr) * s->K + k);
      *(f32x4*)&panel[bb][rr][lane << 2] = v;           // linear dest slot
    }
  }
}

__global__ __launch_bounds__(256, 5) void gemm_skinny(
    const float* __restrict__ Gv2v, const float* __restrict__ Gv2e,
    const float* __restrict__ Ge2e, const float* __restrict__ Ge2f,
    const float* __restrict__ Gf2f, const short* __restrict__ Yt,
    float* __restrict__ out)
{
  __shared__ float panel[2][16][PK];   // exactly 32768 B; reused for reduce

  int bid  = blockIdx.x;
  int lane = threadIdx.x & 63, w = threadIdx.x >> 6;
  int r = lane & 15, g = lane >> 4;

  SegD s0, s1; size_t ob; int tile;
  if (bid < 500) {           // zf = Ge2f@Ye2f + Gf2f@Yf2f
    tile = bid;
    s0 = { Ge2f, Yt + 778240,  12000, 12032, 47 };
    s1 = { Gf2f, Yt + 1163264, 8000,  8192,  32 };
    ob = (size_t)18000 * 32;
  } else if (bid < 1250) {   // ze = Gv2e@Yv2e + Ge2e@Ye2e
    tile = bid - 500;
    s0 = { Gv2e, Yt + 196608,  6000,  6144,  24 };
    s1 = { Ge2e, Yt + 393216,  12000, 12032, 47 };
    ob = (size_t)6000 * 32;
  } else {                   // zv = Gv2v@Yv2v
    tile = bid - 1250;
    s0 = { Gv2v, Yt,           6000,  6144,  24 };
    s1 = { nullptr, nullptr,   0,     0,     0  };
    ob = 0;
  }
  int npT  = s0.np + s1.np;
  int row0 = tile * 16;

  // prologue: FIFO order stage(0) < B(0) < stage(1)
  stage_idx(s0, s1, 0, npT, row0, lane, w, panel);
  s16x8 B0a, B0b, B1a, B1b;            // current panel's B frags (2 si x 2 cols)
  {
    const SegD* sc; int pn; resolve(s0, s1, 0, sc, pn);
    int kg0 = pn * PK + (2 * w + 0) * 32 + g * 8;
    int kg1 = pn * PK + (2 * w + 1) * 32 + g * 8;
    B0a = *(const s16x8*)(sc->Y + (size_t)r        * sc->Kp + kg0);
    B0b = *(const s16x8*)(sc->Y + (size_t)(r + 16) * sc->Kp + kg0);
    B1a = *(const s16x8*)(sc->Y + (size_t)r        * sc->Kp + kg1);
    B1b = *(const s16x8*)(sc->Y + (size_t)(r + 16) * sc->Kp + kg1);
  }
  stage_idx(s0, s1, 1, npT, row0, lane, w, panel);

  f32x4 acc0 = {0.f,0.f,0.f,0.f}, acc1 = {0.f,0.f,0.f,0.f};

  for (int p = 0; p < npT; ++p) {
    // wait: stage(p)+B(p) done, stage(p+1) (if DMA) stays in flight
    if (dma4(s0, s1, p + 1, npT))
      asm volatile("s_waitcnt vmcnt(4)" ::: "memory");
    else
      asm volatile("s_waitcnt vmcnt(0)" ::: "memory");
    __builtin_amdgcn_s_barrier();

    // prefetch B(p+1) into regs (flies during compute)
    s16x8 N0a, N0b, N1a, N1b;
    bool have_next = (p + 1 < npT);
    if (have_next) {
      const SegD* sn; int pn1; resolve(s0, s1, p + 1, sn, pn1);
      int kg0 = pn1 * PK + (2 * w + 0) * 32 + g * 8;
      int kg1 = pn1 * PK + (2 * w + 1) * 32 + g * 8;
      N0a = *(const s16x8*)(sn->Y + (size_t)r        * sn->Kp + kg0);
      N0b = *(const s16x8*)(sn->Y + (size_t)(r + 16) * sn->Kp + kg0);
      N1a = *(const s16x8*)(sn->Y + (size_t)r        * sn->Kp + kg1);
      N1b = *(const s16x8*)(sn->Y + (size_t)(r + 16) * sn->Kp + kg1);
    }

    // compute panel p: pure LDS-read + cvt + MFMA (no global VMEM)
    int b  = p & 1;
    int sw = r & 7;
    const float* rowp = &panel[b][r][0];
    #pragma unroll
    for (int si = 0; si < 2; ++si) {
      int c0 = (2 * w + si) * 8 + g * 2;
      f32x4 a0 = *(const f32x4*)(rowp + (((c0    ) ^ sw) << 2));
      f32x4 a1 = *(const f32x4*)(rowp + (((c0 + 1) ^ sw) << 2));
      s16x8 a;
      a[0] = f2bf(a0.x); a[1] = f2bf(a0.y); a[2] = f2bf(a0.z); a[3] = f2bf(a0.w);
      a[4] = f2bf(a1.x); a[5] = f2bf(a1.y); a[6] = f2bf(a1.z); a[7] = f2bf(a1.w);
      if (si == 0) {
        acc0 = __builtin_amdgcn_mfma_f32_16x16x32_bf16(a, B0a, acc0, 0, 0, 0);
        acc1 = __builtin_amdgcn_mfma_f32_16x16x32_bf16(a, B0b, acc1, 0, 0, 0);
      } else {
        acc0 = __builtin_amdgcn_mfma_f32_16x16x32_bf16(a, B1a, acc0, 0, 0, 0);
        acc1 = __builtin_amdgcn_mfma_f32_16x16x32_bf16(a, B1b, acc1, 0, 0, 0);
      }
    }

    asm volatile("s_waitcnt lgkmcnt(0)" ::: "memory");
    __builtin_amdgcn_sched_barrier(0);
    __builtin_amdgcn_s_barrier();      // all waves done reading buf b
    stage_idx(s0, s1, p + 2, npT, row0, lane, w, panel);  // -> buf b

    if (have_next) { B0a = N0a; B0b = N0b; B1a = N1a; B1b = N1b; }
  }

  // cross-wave reduce (C/D layout: col = lane&15, row = (lane>>4)*4+reg)
  float (*red)[512] = (float (*)[512])panel;   // safe: loop ended fully synced
  #pragma unroll
  for (int q = 0; q < 4; ++q) {
    int rw = g * 4 + q;
    red[w][rw * 32 + r]      = acc0[q];
    red[w][rw * 32 + 16 + r] = acc1[q];
  }
  __syncthreads();
  #pragma unroll
  for (int i = 0; i < 2; ++i) {
    int e = (int)threadIdx.x + i * 256;
    float s = red[0][e] + red[1][e] + red[2][e] + red[3][e];
    out[ob + (size_t)row0 * 32 + e] = s;
  }
}

extern "C" void kernel_launch(void* const* d_in, const int* in_sizes, int n_in,
                              void* d_out, int out_size, void* d_ws, size_t ws_size,
                              hipStream_t stream) {
  const float* xv   = (const float*)d_in[0];
  const float* xe   = (const float*)d_in[1];
  const float* xf   = (const float*)d_in[2];
  const float* Gv2v = (const float*)d_in[3];
  const float* Gv2e = (const float*)d_in[4];
  const float* Ge2e = (const float*)d_in[5];
  const float* Ge2f = (const float*)d_in[6];
  const float* Gf2f = (const float*)d_in[7];
  const float* Wv2v = (const float*)d_in[8];
  const float* Wv2e = (const float*)d_in[9];
  const float* We2e = (const float*)d_in[10];
  const float* We2f = (const float*)d_in[11];
  const float* Wf2f = (const float*)d_in[12];
  short* Yt  = (short*)d_ws;
  float* out = (float*)d_out;

  hipLaunchKernelGGL(build_yt, dim3(174), dim3(256), 0, stream,
                     xv, xe, xf, Wv2v, Wv2e, We2e, We2f, Wf2f, Yt);
  hipLaunchKernelGGL(gemm_skinny, dim3(1625), dim3(256), 0, stream,
                     Gv2v, Gv2e, Ge2e, Ge2f, Gf2f, Yt, out);
}

// Round 6
// 362.751 us; speedup vs baseline: 1.0375x; 1.0375x over previous
//
#include <hip/hip_runtime.h>

typedef float  f32x4 __attribute__((ext_vector_type(4)));
typedef short  s16x8 __attribute__((ext_vector_type(8)));

#define PK   512   // panel K-span (floats): 2KB burst per row
#define PSTR 516   // padded LDS row stride (516%32=4 -> 2-way bank alias, free)

typedef const __attribute__((address_space(1))) float* gas1f;
typedef __attribute__((address_space(3))) float*       las3f;

__device__ __forceinline__ short f2bf(float f) {
  unsigned u = __builtin_bit_cast(unsigned, f);
  u += 0x7FFFu + ((u >> 16) & 1u);   // round-to-nearest-even
  return (short)(u >> 16);
}

// ---------------------------------------------------------------------------
// Kernel 1: Y^T build.  Yt[c][k] = bf16( sum_d x[k][d] * W[d][c] )
// Kpad multiple of 512, zero-filled.  Offsets (elements):
//  v2v 0      (Kpad 6144)  | v2e 196608 (6144) | e2e 393216 (12288)
//  e2f 786432 (12288)      | f2f 1179648 (8192); total 1441792 = 2.88 MB.
// ---------------------------------------------------------------------------
__global__ __launch_bounds__(256) void build_yt(
    const float* __restrict__ xv, const float* __restrict__ xe,
    const float* __restrict__ xf,
    const float* __restrict__ Wv2v, const float* __restrict__ Wv2e,
    const float* __restrict__ We2e, const float* __restrict__ We2f,
    const float* __restrict__ Wf2f, short* __restrict__ Yt)
{
  int bid = blockIdx.x;
  const float* x; const float* W; int K, Kpad; size_t yoff;
  if (bid < 24)       { x=xv; W=Wv2v; K=6000;  Kpad=6144;  yoff=0;       }
  else if (bid < 48)  { x=xv; W=Wv2e; K=6000;  Kpad=6144;  yoff=196608;  bid-=24; }
  else if (bid < 96)  { x=xe; W=We2e; K=12000; Kpad=12288; yoff=393216;  bid-=48; }
  else if (bid < 144) { x=xe; W=We2f; K=12000; Kpad=12288; yoff=786432;  bid-=96; }
  else                { x=xf; W=Wf2f; K=8000;  Kpad=8192;  yoff=1179648; bid-=144; }

  __shared__ float Wl[32][32];
  int tid = threadIdx.x;
  #pragma unroll
  for (int i = 0; i < 4; ++i) {
    int e = tid + i * 256;
    Wl[e >> 5][e & 31] = W[e];
  }
  __syncthreads();

  int row = bid * 256 + tid;
  if (row >= Kpad) return;

  float acc[32];
  #pragma unroll
  for (int c = 0; c < 32; ++c) acc[c] = 0.f;

  if (row < K) {
    const float* xp = x + (size_t)row * 32;
    float xr[32];
    #pragma unroll
    for (int i = 0; i < 8; ++i) {
      f32x4 v = *(const f32x4*)(xp + i * 4);
      xr[i*4+0] = v.x; xr[i*4+1] = v.y; xr[i*4+2] = v.z; xr[i*4+3] = v.w;
    }
    #pragma unroll
    for (int d = 0; d < 32; ++d) {
      float xd = xr[d];
      #pragma unroll
      for (int c = 0; c < 32; ++c) acc[c] += xd * Wl[d][c];
    }
  }
  #pragma unroll
  for (int c = 0; c < 32; ++c)
    Yt[yoff + (size_t)c * Kpad + row] = f2bf(acc[c]);
}

// ---------------------------------------------------------------------------
// Kernel 2: skinny GEMM.
//  - A staged in LDS panels [16][512]f (66KB dbuf, 2 blocks/CU): per row a
//    2KB CONTIGUOUS burst via 2x global_load_lds dwordx4 (8 DMA/wave/panel)
//  - counted-vmcnt pipeline, never drained to 0 on full panels:
//    FIFO per wave:  ... B(p) < stage(p+1) < B(p+1) < stage(p+2) ...
//    top-of-iter vmcnt(8) leaves stage(p+1) in flight; compute = LDS+regs only
//  - B (Yt, L2-resident) prefetched to regs one panel ahead
// ---------------------------------------------------------------------------
__device__ __forceinline__ void stage_panel(
    const float* __restrict__ G, int K, int row0, int pn, int lane, int w,
    float (*panel)[16][PSTR], int bb)
{
  if ((pn + 1) * PK <= K) {            // full panel: 2x 1KB DMA per row
    #pragma unroll
    for (int j = 0; j < 4; ++j) {
      int rr = 4 * w + j;
      const float* base = G + (size_t)(row0 + rr) * K + pn * PK;
      __builtin_amdgcn_global_load_lds((gas1f)(base + lane * 4),
                                       (las3f)&panel[bb][rr][0],   16, 0, 2);
      __builtin_amdgcn_global_load_lds((gas1f)(base + 256 + lane * 4),
                                       (las3f)&panel[bb][rr][256], 16, 0, 2);
    }
  } else {                             // tail: reg-staged, masked, zero-filled
    #pragma unroll
    for (int j = 0; j < 4; ++j) {
      int rr = 4 * w + j;
      #pragma unroll
      for (int h = 0; h < 2; ++h) {
        int k = pn * PK + h * 256 + lane * 4;
        f32x4 v = {0.f, 0.f, 0.f, 0.f};
        if (k < K) v = *(const f32x4*)(G + (size_t)(row0 + rr) * K + k);
        *(f32x4*)&panel[bb][rr][h * 256 + lane * 4] = v;
      }
    }
  }
}

__device__ __forceinline__ void loadB(const short* __restrict__ Y, int Kp,
                                      int r, int g, int w, int p, s16x8 B[4][2])
{
  #pragma unroll
  for (int si = 0; si < 4; ++si) {
    int kg = p * PK + (4 * w + si) * 32 + g * 8;
    B[si][0] = *(const s16x8*)(Y + (size_t)r        * Kp + kg);
    B[si][1] = *(const s16x8*)(Y + (size_t)(r + 16) * Kp + kg);
  }
}

__device__ __forceinline__ void seg_run(
    const float* __restrict__ G, const short* __restrict__ Yt,
    int K, int Kp, int np, int row0, int lane, int w,
    float (*panel)[16][PSTR], f32x4& acc0, f32x4& acc1)
{
  int r = lane & 15, g = lane >> 4;
  s16x8 Bc[4][2], Bn[4][2];

  // prologue, FIFO order: stage(0) < B(0) < stage(1)
  stage_panel(G, K, row0, 0, lane, w, panel, 0);
  loadB(Yt, Kp, r, g, w, 0, Bc);
  if (np > 1) stage_panel(G, K, row0, 1, lane, w, panel, 1);

  for (int p = 0; p < np; ++p) {
    if (p + 1 < np && (p + 2) * PK <= K)      // panel p+1 was DMA-staged
      asm volatile("s_waitcnt vmcnt(8)" ::: "memory");
    else
      asm volatile("s_waitcnt vmcnt(0)" ::: "memory");
    __builtin_amdgcn_s_barrier();

    int b = p & 1;
    const float* rowp = &panel[b][r][0];
    #pragma unroll
    for (int si = 0; si < 4; ++si) {
      int kk = (4 * w + si) * 32 + g * 8;
      f32x4 a0 = *(const f32x4*)(rowp + kk);
      f32x4 a1 = *(const f32x4*)(rowp + kk + 4);
      s16x8 a;
      a[0] = f2bf(a0.x); a[1] = f2bf(a0.y); a[2] = f2bf(a0.z); a[3] = f2bf(a0.w);
      a[4] = f2bf(a1.x); a[5] = f2bf(a1.y); a[6] = f2bf(a1.z); a[7] = f2bf(a1.w);
      acc0 = __builtin_amdgcn_mfma_f32_16x16x32_bf16(a, Bc[si][0], acc0, 0, 0, 0);
      acc1 = __builtin_amdgcn_mfma_f32_16x16x32_bf16(a, Bc[si][1], acc1, 0, 0, 0);
    }

    // issue B(p+1) before the barrier so it flies across it (FIFO: < stage(p+2))
    if (p + 1 < np) loadB(Yt, Kp, r, g, w, p + 1, Bn);

    asm volatile("s_waitcnt lgkmcnt(0)" ::: "memory");
    __builtin_amdgcn_sched_barrier(0);
    __builtin_amdgcn_s_barrier();      // all waves done reading buf b
    if (p + 2 < np) stage_panel(G, K, row0, p + 2, lane, w, panel, b);

    if (p + 1 < np) {                  // copy-wait = vmcnt(8): leaves stage(p+2)
      #pragma unroll
      for (int si = 0; si < 4; ++si) {
        Bc[si][0] = Bn[si][0]; Bc[si][1] = Bn[si][1];
      }
    }
  }
  __syncthreads();                     // segment epilogue: full drain
}

__global__ __launch_bounds__(256, 2) void gemm_skinny(
    const float* __restrict__ Gv2v, const float* __restrict__ Gv2e,
    const float* __restrict__ Ge2e, const float* __restrict__ Ge2f,
    const float* __restrict__ Gf2f, const short* __restrict__ Yt,
    float* __restrict__ out)
{
  __shared__ float panel[2][16][PSTR];   // 66048 B; reused for reduce

  int bid  = blockIdx.x;
  int lane = threadIdx.x & 63, w = threadIdx.x >> 6;

  const float *G0, *G1; const short *Y0, *Y1;
  int K0, Kp0, n0, K1, Kp1, n1, tile; size_t ob;
  if (bid < 500) {           // zf = Ge2f@Ye2f + Gf2f@Yf2f  (heaviest first)
    tile = bid;
    G0 = Ge2f; Y0 = Yt + 786432;  K0 = 12000; Kp0 = 12288; n0 = 24;
    G1 = Gf2f; Y1 = Yt + 1179648; K1 = 8000;  Kp1 = 8192;  n1 = 16;
    ob = (size_t)18000 * 32;
  } else if (bid < 1250) {   // ze = Gv2e@Yv2e + Ge2e@Ye2e
    tile = bid - 500;
    G0 = Gv2e; Y0 = Yt + 196608;  K0 = 6000;  Kp0 = 6144;  n0 = 12;
    G1 = Ge2e; Y1 = Yt + 393216;  K1 = 12000; Kp1 = 12288; n1 = 24;
    ob = (size_t)6000 * 32;
  } else {                   // zv = Gv2v@Yv2v
    tile = bid - 1250;
    G0 = Gv2v; Y0 = Yt;           K0 = 6000;  Kp0 = 6144;  n0 = 12;
    G1 = nullptr; Y1 = nullptr;   K1 = 0; Kp1 = 0; n1 = 0;
    ob = 0;
  }
  int row0 = tile * 16;

  f32x4 acc0 = {0.f,0.f,0.f,0.f}, acc1 = {0.f,0.f,0.f,0.f};
  seg_run(G0, Y0, K0, Kp0, n0, row0, lane, w, panel, acc0, acc1);
  if (G1) seg_run(G1, Y1, K1, Kp1, n1, row0, lane, w, panel, acc0, acc1);

  // cross-wave reduce (C/D layout: col = lane&15, row = (lane>>4)*4+reg)
  float (*red)[512] = (float (*)[512])panel;   // safe: seg_run ends synced
  int r = lane & 15, g = lane >> 4;
  #pragma unroll
  for (int q = 0; q < 4; ++q) {
    int rw = g * 4 + q;
    red[w][rw * 32 + r]      = acc0[q];
    red[w][rw * 32 + 16 + r] = acc1[q];
  }
  __syncthreads();
  #pragma unroll
  for (int i = 0; i < 2; ++i) {
    int e = (int)threadIdx.x + i * 256;
    float s = red[0][e] + red[1][e] + red[2][e] + red[3][e];
    out[ob + (size_t)row0 * 32 + e] = s;
  }
}

extern "C" void kernel_launch(void* const* d_in, const int* in_sizes, int n_in,
                              void* d_out, int out_size, void* d_ws, size_t ws_size,
                              hipStream_t stream) {
  const float* xv   = (const float*)d_in[0];
  const float* xe   = (const float*)d_in[1];
  const float* xf   = (const float*)d_in[2];
  const float* Gv2v = (const float*)d_in[3];
  const float* Gv2e = (const float*)d_in[4];
  const float* Ge2e = (const float*)d_in[5];
  const float* Ge2f = (const float*)d_in[6];
  const float* Gf2f = (const float*)d_in[7];
  const float* Wv2v = (const float*)d_in[8];
  const float* Wv2e = (const float*)d_in[9];
  const float* We2e = (const float*)d_in[10];
  const float* We2f = (const float*)d_in[11];
  const float* Wf2f = (const float*)d_in[12];
  short* Yt  = (short*)d_ws;
  float* out = (float*)d_out;

  hipLaunchKernelGGL(build_yt, dim3(176), dim3(256), 0, stream,
                     xv, xe, xf, Wv2v, Wv2e, We2e, We2f, Wf2f, Yt);
  hipLaunchKernelGGL(gemm_skinny, dim3(1625), dim3(256), 0, stream,
                     Gv2v, Gv2e, Ge2e, Ge2f, Gf2f, Yt, out);
}